// Round 2
// 106.769 us; speedup vs baseline: 1.0191x; 1.0191x over previous
//
#include <hip/hip_runtime.h>
#include <cmath>

#define D 128
#define BM 128   // block tile (rows and cols)
#define NSEG 8   // segments per strip-pair
#define LOG2E 1.4426950408889634

typedef __attribute__((ext_vector_type(8))) _Float16 f16x8;
typedef __attribute__((ext_vector_type(4))) float f32x4;
typedef __attribute__((ext_vector_type(2))) float f32x2;

// async global->LDS 16B copy (global_load_lds_dwordx4); LDS dst is
// wave-uniform base + lane*16 -- swizzle lives in gsrc.
// R9/R10 post-mortem: ALWAYS pass 0 for the builtin's immediate offset;
// fold offsets into the pointer.
__device__ __forceinline__ void async_cp16(const void* g, void* l) {
    __builtin_amdgcn_global_load_lds(
        (__attribute__((address_space(1))) void*)g,
        (__attribute__((address_space(3))) void*)l, 16, 0, 0);
}

// ---------------------------------------------------------------------------
// Prep: fp32 x -> fp16 (RTN) combined [x1; x2], per-row El[r] =
// -gamma*log2e*|row|^2 (log2-domain), AND zero the 64 acc slots (block 0).
// ---------------------------------------------------------------------------
__global__ __launch_bounds__(256) void prep_kernel(
    const float* __restrict__ x1, const float* __restrict__ x2,
    _Float16* __restrict__ xh, float* __restrict__ El,
    double* __restrict__ acc, float gl, int N) {
    int tid = threadIdx.x;
    if (blockIdx.x == 0 && tid < 64) acc[tid] = 0.0;
    int r = blockIdx.x * 16 + (tid >> 4);
    if (r >= 2 * N) return;
    int l = tid & 15;
    const float* row = (r < N) ? x1 + (size_t)r * D : x2 + (size_t)(r - N) * D;
    float4 v0 = ((const float4*)row)[l * 2];
    float4 v1 = ((const float4*)row)[l * 2 + 1];
    float v[8] = {v0.x, v0.y, v0.z, v0.w, v1.x, v1.y, v1.z, v1.w};
    float p = 0.f;
    _Float16 h8[8];
#pragma unroll
    for (int j = 0; j < 8; ++j) {
        p = fmaf(v[j], v[j], p);
        h8[j] = (_Float16)v[j];   // RTN-even
    }
    *(uint4*)(xh + (size_t)r * D + l * 8) = *(uint4*)h8;
#pragma unroll
    for (int off = 8; off; off >>= 1) p += __shfl_down(p, off, 16);
    if (l == 0) El[r] = gl * p;   // gl = -gamma*log2e
}

// ---------------------------------------------------------------------------
// R11 (resubmit R12 -- round 1 bench was GPUAcquisitionTimeout, no data):
// strip-persistent pipeline. Previous structure (1 tile/block, 2-chunk
// stage->drain->compute) measured MfmaUtil 27% / Occ 33% / no pipe >50%:
// latency/barrier-bound. This version:
//   * 64 strip-pairs (bi=p with bi=127-p -> constant 129 tiles), x8 segments
//     = 512 blocks of ~16 tiles; exactly 2 resident blocks/CU (LDS 64 KiB).
//   * A-operand (64 rows x K=128 per wave) held in REGISTERS (16x f16x8),
//     loaded direct from L2-resident xh, reloaded at most once per block.
//     A never touches LDS -> LDS-read floor halves, staged L2 traffic halves.
//   * B double-buffered in LDS, global_load_lds + XOR swizzle (granule ^
//     (row&7), same guarantee as R2-R8: 2-way max = free).
//   * 2-deep prefetch with RAW s_barrier + counted "s_waitcnt vmcnt(8)":
//     tile t+1's 8 loads stay in flight across ALL of tile t's compute.
//     __syncthreads() would drain vmcnt(0) -> never used inside the loop.
//   * epilogue exp2 folded as before; per-thread f64 accumulation across
//     tiles, ONE shuffle-reduce + atomicAdd per block (not per tile).
// Signed weight: bi==bj: +1; same class off-diag: +2; cross class: -2.
// MFMA: v_mfma_f32_16x16x32_f16 (m89/m91-HW-verified layout), unchanged.
// VGPR budget: a[4][4]=64 + C[4][4]=64 + b[4]=16 + misc ~ 225 < 256 at
// launch_bounds(256,2). Tripwire: WRITE_SIZE must stay KB-scale (spill).
// ---------------------------------------------------------------------------
__global__ __launch_bounds__(256, 2) void mmd_mfma_kernel(
    const _Float16* __restrict__ xh, const float* __restrict__ El,
    double* __restrict__ acc, float c2l, int N) {
    __shared__ float4 smem[2][2048];  // 64 KiB: two 32 KiB B buffers

    int tid = threadIdx.x;
    int lane = tid & 63, wave = tid >> 6;
    int quad = lane >> 4, l16 = lane & 15;
    int wrow = (wave & 1) * 64, wcol = (wave >> 1) * 64;

    int nt2 = 2 * N / BM;        // 128 combined block-rows
    int half = N / BM;           // first `half` are x1
    int p = blockIdx.x >> 3;     // strip pair: rows p and nt2-1-p
    int s = blockIdx.x & (NSEG - 1);
    int tpp = nt2 + 1;           // tiles per pair (129)
    int q = tpp / NSEG, r = tpp % NSEG;
    int t0 = s * q + (s < r ? s : r);
    int nt = q + (s < r ? 1 : 0);    // 16 or 17 tiles, nt >= 2 always

    // per-thread staging geometry: slot i*256+tid, row = slot>>4 (16 float4
    // granules per row of K=128), granule XOR-swizzled by row&7.
    int goff[8], lslot[8];
#pragma unroll
    for (int i = 0; i < 8; ++i) {
        int slot = i * 256 + tid;
        int row = slot >> 4;
        int g = (slot & 15) ^ (row & 7);
        goff[i] = row * D + g * 8;
        lslot[i] = slot;
    }

    auto stage = [&](int bBase, int buf) {
        const _Float16* src = xh + (size_t)bBase * D;
#pragma unroll
        for (int i = 0; i < 8; ++i)
            async_cp16(src + goff[i], &smem[buf][lslot[i]]);
    };
    auto BI = [&](int tt) { return tt <= p ? p : nt2 - 1 - p; };
    auto BJ = [&](int tt) { return tt <= p ? tt : tt - p - 1; };

    // prologue: fill both buffers (tiles t0, t0+1)
    stage(BJ(t0) * BM, 0);
    stage(BJ(t0 + 1) * BM, 1);

    f16x8 a[4][4];       // A fragments: rows wrow..+64, full K=128
    float4 ea4[4];       // A-side El (log2-domain row norms)
    int curA = -1;
    double dsum = 0.0;

    for (int i = 0; i < nt; ++i) {
        int tt = t0 + i;
        int bi = BI(tt), bj = BJ(tt);
        int aBase = bi * BM, bBase = bj * BM;
        float w = (bi == bj) ? 1.0f : 2.0f;
        if ((bi < half) != (bj < half)) w = -2.0f;
        int cur = i & 1;

        // counted wait: tile i's 8 loads are the oldest; tile i+1's 8 (if
        // issued) may stay in flight. NEVER vmcnt(0) mid-loop.
        if (i + 1 < nt) {
            asm volatile("s_waitcnt vmcnt(8)" ::: "memory");
        } else {
            asm volatile("s_waitcnt vmcnt(0)" ::: "memory");
        }
        __builtin_amdgcn_s_barrier();
        __builtin_amdgcn_sched_barrier(0);

        // A reload only when the strip row changes (<= once per block).
        // Placed AFTER the wait: issuing vmem here cannot over-drain the
        // counted wait above.
        if (aBase != curA) {
            curA = aBase;
#pragma unroll
            for (int u = 0; u < 4; ++u) {
                int ar = aBase + wrow + u * 16 + l16;
#pragma unroll
                for (int j = 0; j < 4; ++j) {
                    int g = (j >> 1) * 8 + (j & 1) * 4 + quad;
                    a[u][j] = *(const f16x8*)(xh + (size_t)ar * D + g * 8);
                }
            }
            int arow0 = aBase + wrow + quad * 4;
#pragma unroll
            for (int ti = 0; ti < 4; ++ti)
                ea4[ti] = *(const float4*)&El[arow0 + ti * 16];
        }

        // B-side El, issued early so its wait lands after compute
        int bcol0 = bBase + wcol + l16;
        float ebv[4];
#pragma unroll
        for (int tj = 0; tj < 4; ++tj) ebv[tj] = El[bcol0 + tj * 16];

        f32x4 C[4][4];
#pragma unroll
        for (int ti = 0; ti < 4; ++ti)
#pragma unroll
            for (int tj = 0; tj < 4; ++tj) C[ti][tj] = {0.f, 0.f, 0.f, 0.f};

#pragma unroll
        for (int j = 0; j < 4; ++j) {
            int gb = (j >> 1) * 8 + (j & 1) * 4 + quad;
            f16x8 b[4];
#pragma unroll
            for (int u = 0; u < 4; ++u) {
                int br = wcol + u * 16 + l16;
                b[u] = *(const f16x8*)&smem[cur][br * 16 + (gb ^ (br & 7))];
            }
            __builtin_amdgcn_s_setprio(1);
#pragma unroll
            for (int ti = 0; ti < 4; ++ti)
#pragma unroll
                for (int tj = 0; tj < 4; ++tj)
                    C[ti][tj] = __builtin_amdgcn_mfma_f32_16x16x32_f16(
                        a[ti][j], b[tj], C[ti][tj], 0, 0, 0);
            __builtin_amdgcn_s_setprio(0);
        }

        // epilogue: entry = exp2(c2l*d + ea) * 2^eb; accumulate in f64 regs.
        // C/D layout (m89-verified): col = lane&15, row = quad*4 + reg.
        f32x2 cc = {c2l, c2l};
        float lsum = 0.f;
#pragma unroll
        for (int tj = 0; tj < 4; ++tj) {
            f32x2 p2 = {0.f, 0.f};
#pragma unroll
            for (int ti = 0; ti < 4; ++ti) {
                f32x4 d = C[ti][tj];
                f32x2 a01 = cc * f32x2{d.x, d.y} + f32x2{ea4[ti].x, ea4[ti].y};
                f32x2 a23 = cc * f32x2{d.z, d.w} + f32x2{ea4[ti].z, ea4[ti].w};
                f32x2 e, e2;
                e.x = __builtin_amdgcn_exp2f(a01.x);
                e.y = __builtin_amdgcn_exp2f(a01.y);
                e2.x = __builtin_amdgcn_exp2f(a23.x);
                e2.y = __builtin_amdgcn_exp2f(a23.y);
                p2 += e + e2;
            }
            lsum = fmaf(p2.x + p2.y, __builtin_amdgcn_exp2f(ebv[tj]), lsum);
        }
        dsum += (double)lsum * (double)w;

        // all waves done reading buf[cur] -> safe to overwrite with tile t+2
        __builtin_amdgcn_sched_barrier(0);
        __builtin_amdgcn_s_barrier();
        __builtin_amdgcn_sched_barrier(0);
        if (i + 2 < nt) stage(BJ(tt + 2) * BM, cur);
    }

    // block reduction (once per block, not per tile)
#pragma unroll
    for (int off = 32; off; off >>= 1) dsum += __shfl_down(dsum, off);
    double* red = (double*)&smem[0][0];
    if (lane == 0) red[wave] = dsum;
    __syncthreads();
    if (tid == 0)
        atomicAdd(&acc[blockIdx.x & 63], red[0] + red[1] + red[2] + red[3]);
}

// ---------------------------------------------------------------------------
// Finalize: out = sqrt(max(S/N^2, 0)), S already = S11 + S22 - 2*S12.
// ---------------------------------------------------------------------------
__global__ __launch_bounds__(64) void mmd_finalize_kernel(
    const double* __restrict__ acc, float* __restrict__ out, int N) {
    int l = threadIdx.x;
    double v = acc[l];
#pragma unroll
    for (int off = 32; off; off >>= 1) v += __shfl_down(v, off);
    if (l == 0) {
        double nn = (double)N * (double)N;
        double s = v / nn;
        out[0] = (float)sqrt(s > 0.0 ? s : 0.0);
    }
}

extern "C" void kernel_launch(void* const* d_in, const int* in_sizes, int n_in,
                              void* d_out, int out_size, void* d_ws, size_t ws_size,
                              hipStream_t stream) {
    const float* x1 = (const float*)d_in[0];
    const float* x2 = (const float*)d_in[1];
    int N = in_sizes[0] / D;  // 8192

    // ws layout: [0,512) acc (64 doubles); El @8192 (2N f32);
    // xh @73728 (2N*128 fp16 = 4 MB). Total ~4.07 MB.
    double* acc = (double*)d_ws;
    float* El = (float*)((char*)d_ws + 8192);
    _Float16* xh = (_Float16*)((char*)d_ws + 73728);

    double lg = lgamma(0.5 * (D + 1)) - lgamma(0.5 * D);
    double gz = 2.0 * exp(lg);
    double gamma = 1.0 / (2.0 * gz * gz);
    float gl = (float)(-gamma * LOG2E);        // El scale
    float c2l = (float)(2.0 * gamma * LOG2E);  // dot scale (log2 domain)

    prep_kernel<<<(2 * N + 15) / 16, 256, 0, stream>>>(x1, x2, xh, El, acc, gl, N);

    int nt2 = 2 * N / BM;                 // 128
    int nblocks = (nt2 / 2) * NSEG;       // 64 pairs x 8 segments = 512
    mmd_mfma_kernel<<<nblocks, 256, 0, stream>>>(xh, El, acc, c2l, N);

    mmd_finalize_kernel<<<1, 64, 0, stream>>>(acc, (float*)d_out, N);
}